// Round 1
// baseline (206.205 us; speedup 1.0000x reference)
//
#include <hip/hip_runtime.h>
#include <stdint.h>

#define N_NODES 8192
#define N_EDGES 262144
#define IN_C    512
#define OUT_C   512
#define MAX_DEG 512   // Poisson(32) max degree is ~70 for this fixed input; 512 is a huge margin

typedef __attribute__((ext_vector_type(8))) short short8;   // 8 bf16 in 4 VGPRs (guide §3)
typedef __attribute__((ext_vector_type(4))) float f32x4;

// ---- fp32 -> bf16 (RNE) ----
__device__ inline uint16_t f2bf(float f) {
    uint32_t u = __float_as_uint(f);
    uint32_t r = (u + 0x7FFFu + ((u >> 16) & 1u)) >> 16;
    return (uint16_t)r;
}

__global__ void f32_to_bf16_k(const float* __restrict__ in, uint16_t* __restrict__ out, int n) {
    int i = (blockIdx.x * 256 + threadIdx.x) * 4;
    if (i >= n) return;
    float4 v = *(const float4*)(in + i);
    ushort4 o;
    o.x = f2bf(v.x); o.y = f2bf(v.y); o.z = f2bf(v.z); o.w = f2bf(v.w);
    *(ushort4*)(out + i) = o;
}

// ---- graph build: dedupe via bitmap, exact degree, fixed-stride neighbor list ----
__global__ void build_graph_k(const int* __restrict__ ei, uint32_t* __restrict__ bitmap,
                              int* __restrict__ cnt, uint16_t* __restrict__ nbr) {
    int t = blockIdx.x * blockDim.x + threadIdx.x;
    int r, c;
    if (t < N_EDGES) {
        r = ei[t];             // edge_index[0][t]
        c = ei[N_EDGES + t];   // edge_index[1][t]
    } else if (t < N_EDGES + N_NODES) {
        r = t - N_EDGES; c = r;   // self loop
    } else return;
    uint32_t bitidx = (uint32_t)r * N_NODES + (uint32_t)c;   // < 2^26
    uint32_t word = bitidx >> 5;
    uint32_t mask = 1u << (bitidx & 31u);
    uint32_t old = atomicOr(&bitmap[word], mask);
    if (!(old & mask)) {                      // winner: first setter of this (r,c)
        int pos = atomicAdd(&cnt[r], 1);
        if (pos < MAX_DEG) nbr[r * MAX_DEG + pos] = (uint16_t)c;
    }
}

__global__ void compute_dis_k(const int* __restrict__ cnt, float* __restrict__ dis) {
    int i = blockIdx.x * 256 + threadIdx.x;
    if (i < N_NODES) dis[i] = rsqrtf((float)cnt[i]);   // cnt >= 1 (self loop)
}

// ---- h = x @ W^T + b   (bf16 MFMA 16x16x32, fp32 accum) ----
// block = 256 thr (4 waves); block tile 64 rows x 64 cols; wave w -> rows m_base+16w, 4 col subtiles
__global__ __launch_bounds__(256) void gemm_hb_k(const uint16_t* __restrict__ xb,
                                                 const uint16_t* __restrict__ wb,
                                                 const float* __restrict__ bias,
                                                 float* __restrict__ h) {
    const int wave = threadIdx.x >> 6;
    const int lane = threadIdx.x & 63;
    const int quad = lane >> 4;
    const int l16  = lane & 15;
    const int m_base = blockIdx.y * 64 + wave * 16;
    const int n_base = blockIdx.x * 64;

    f32x4 acc[4];
    #pragma unroll
    for (int s = 0; s < 4; s++) acc[s] = (f32x4){0.f, 0.f, 0.f, 0.f};

    const uint16_t* xrow = xb + (m_base + l16) * IN_C + quad * 8;   // A[m=lane&15][k=quad*8+j]
    #pragma unroll 4
    for (int k0 = 0; k0 < IN_C; k0 += 32) {
        short8 a = *(const short8*)(xrow + k0);
        #pragma unroll
        for (int s = 0; s < 4; s++) {
            // B[k][n] = W[n][k]; lane holds n=lane&15, k=quad*8+j -> contiguous read of W row
            const uint16_t* wrow = wb + (n_base + s * 16 + l16) * IN_C + quad * 8 + k0;
            short8 b = *(const short8*)wrow;
            acc[s] = __builtin_amdgcn_mfma_f32_16x16x32_bf16(a, b, acc[s], 0, 0, 0);
        }
    }
    // C/D: col = lane&15, row = quad*4 + reg   (guide §3, m89/m91-verified)
    const int row = m_base + quad * 4;
    #pragma unroll
    for (int s = 0; s < 4; s++) {
        int col = n_base + s * 16 + l16;
        float bv = bias[col];
        #pragma unroll
        for (int r = 0; r < 4; r++)
            h[(row + r) * OUT_C + col] = acc[s][r] + bv;
    }
}

// ---- out[i] = dis[i] * sum_j dis[j] * h[j]  over neighbor list ----
__global__ __launch_bounds__(256) void aggregate_k(const int* __restrict__ cnt,
                                                   const uint16_t* __restrict__ nbr,
                                                   const float* __restrict__ dis,
                                                   const float* __restrict__ h,
                                                   float* __restrict__ out) {
    const int i = blockIdx.x;
    int m = cnt[i]; if (m > MAX_DEG) m = MAX_DEG;

    __shared__ uint16_t jl[MAX_DEG];
    __shared__ float    dl[MAX_DEG];
    for (int t = threadIdx.x; t < m; t += 256) {
        uint16_t j = nbr[i * MAX_DEG + t];
        jl[t] = j;
        dl[t] = dis[j];
    }
    __syncthreads();

    const int c0 = threadIdx.x, c1 = threadIdx.x + 256;
    float s0 = 0.f, s1 = 0.f;
    for (int l = 0; l < m; l++) {
        int j = (int)jl[l];          // LDS broadcast
        float dj = dl[l];
        s0 += dj * h[j * OUT_C + c0];   // coalesced across threads
        s1 += dj * h[j * OUT_C + c1];
    }
    float di = dis[i];
    out[i * OUT_C + c0] = di * s0;
    out[i * OUT_C + c1] = di * s1;
}

extern "C" void kernel_launch(void* const* d_in, const int* in_sizes, int n_in,
                              void* d_out, int out_size, void* d_ws, size_t ws_size,
                              hipStream_t stream) {
    const float* x  = (const float*)d_in[0];
    const int*   ei = (const int*)  d_in[1];
    const float* W  = (const float*)d_in[2];
    const float* b  = (const float*)d_in[3];
    float* out = (float*)d_out;
    char* ws = (char*)d_ws;

    // ws layout (bytes)
    const size_t BITMAP_OFF = 0;                       // 8 MB
    const size_t CNT_OFF    = 8388608;                 // 32 KB
    const size_t DIS_OFF    = CNT_OFF + 32768;         // 32 KB
    const size_t NBR_OFF    = DIS_OFF + 32768;         // 8 MB  (u16 * 8192 * 512)
    const size_t XB_OFF     = NBR_OFF + 8388608;       // 8 MB
    const size_t WB_OFF     = XB_OFF + 8388608;        // 512 KB
    const size_t H_OFF      = WB_OFF + 524288;         // 16 MB
    uint32_t* bitmap = (uint32_t*)(ws + BITMAP_OFF);
    int*      cnt    = (int*)     (ws + CNT_OFF);
    float*    dis    = (float*)   (ws + DIS_OFF);
    uint16_t* nbr    = (uint16_t*)(ws + NBR_OFF);
    uint16_t* xb     = (uint16_t*)(ws + XB_OFF);
    uint16_t* wb     = (uint16_t*)(ws + WB_OFF);
    float*    h      = (float*)   (ws + H_OFF);

    hipMemsetAsync(bitmap, 0, 8388608, stream);
    hipMemsetAsync(cnt, 0, 32768, stream);

    f32_to_bf16_k<<<(N_NODES * IN_C / 4 + 255) / 256, 256, 0, stream>>>(x, xb, N_NODES * IN_C);
    f32_to_bf16_k<<<(OUT_C * IN_C / 4 + 255) / 256, 256, 0, stream>>>(W, wb, OUT_C * IN_C);

    build_graph_k<<<(N_EDGES + N_NODES + 255) / 256, 256, 0, stream>>>(ei, bitmap, cnt, nbr);
    compute_dis_k<<<(N_NODES + 255) / 256, 256, 0, stream>>>(cnt, dis);

    gemm_hb_k<<<dim3(OUT_C / 64, N_NODES / 64), 256, 0, stream>>>(xb, wb, b, h);

    aggregate_k<<<N_NODES, 256, 0, stream>>>(cnt, nbr, dis, h, out);
}

// Round 2
// 147.856 us; speedup vs baseline: 1.3946x; 1.3946x over previous
//
#include <hip/hip_runtime.h>
#include <stdint.h>

#define N_NODES 8192
#define N_EDGES 262144
#define IN_C    512
#define OUT_C   512
#define MAX_DEG 512   // Poisson(~33) max degree is ~70 for this fixed input; 512 is a huge margin

typedef __attribute__((ext_vector_type(8))) short short8;   // 8 bf16 in 4 VGPRs (guide §3)
typedef __attribute__((ext_vector_type(4))) float f32x4;

// ---- fp32 -> bf16 (RNE) ----
__device__ inline uint16_t f2bf(float f) {
    uint32_t u = __float_as_uint(f);
    uint32_t r = (u + 0x7FFFu + ((u >> 16) & 1u)) >> 16;
    return (uint16_t)r;
}

__global__ void f32_to_bf16_k(const float* __restrict__ in, uint16_t* __restrict__ out, int n) {
    int i = (blockIdx.x * 256 + threadIdx.x) * 4;
    if (i >= n) return;
    float4 v = *(const float4*)(in + i);
    ushort4 o;
    o.x = f2bf(v.x); o.y = f2bf(v.y); o.z = f2bf(v.z); o.w = f2bf(v.w);
    *(ushort4*)(out + i) = o;
}

// ---- graph build: dedupe via bitmap, exact degree, fixed-stride neighbor list ----
__global__ void build_graph_k(const int* __restrict__ ei, uint32_t* __restrict__ bitmap,
                              int* __restrict__ cnt, uint16_t* __restrict__ nbr) {
    int t = blockIdx.x * blockDim.x + threadIdx.x;
    int r, c;
    if (t < N_EDGES) {
        r = ei[t];             // edge_index[0][t]
        c = ei[N_EDGES + t];   // edge_index[1][t]
    } else if (t < N_EDGES + N_NODES) {
        r = t - N_EDGES; c = r;   // self loop
    } else return;
    uint32_t bitidx = (uint32_t)r * N_NODES + (uint32_t)c;   // < 2^26
    uint32_t word = bitidx >> 5;
    uint32_t mask = 1u << (bitidx & 31u);
    uint32_t old = atomicOr(&bitmap[word], mask);
    if (!(old & mask)) {                      // winner: first setter of this (r,c)
        int pos = atomicAdd(&cnt[r], 1);
        if (pos < MAX_DEG) nbr[r * MAX_DEG + pos] = (uint16_t)c;
    }
}

// ---- h = x @ W^T + b   (bf16 MFMA 16x16x32, fp32 accum, bf16 output) ----
// block = 256 thr (4 waves); block tile 256 rows x 64 cols; each wave 64x64 (4 A-frags x 4 B-frags)
__global__ __launch_bounds__(256) void gemm_hb_k(const uint16_t* __restrict__ xb,
                                                 const uint16_t* __restrict__ wb,
                                                 const float* __restrict__ bias,
                                                 uint16_t* __restrict__ h) {
    const int wave = threadIdx.x >> 6;
    const int lane = threadIdx.x & 63;
    const int quad = lane >> 4;
    const int l16  = lane & 15;
    const int m_base = blockIdx.y * 256 + wave * 64;
    const int n_base = blockIdx.x * 64;

    f32x4 acc[4][4];
    #pragma unroll
    for (int a = 0; a < 4; a++)
        #pragma unroll
        for (int s = 0; s < 4; s++) acc[a][s] = (f32x4){0.f, 0.f, 0.f, 0.f};

    for (int k0 = 0; k0 < IN_C; k0 += 32) {
        short8 af[4], bf[4];
        #pragma unroll
        for (int a = 0; a < 4; a++)   // A[m=lane&15][k=quad*8+j]
            af[a] = *(const short8*)(xb + (m_base + a * 16 + l16) * IN_C + quad * 8 + k0);
        #pragma unroll
        for (int s = 0; s < 4; s++)   // B[k][n] = W[n][k]: lane n=lane&15, k=quad*8+j
            bf[s] = *(const short8*)(wb + (n_base + s * 16 + l16) * IN_C + quad * 8 + k0);
        #pragma unroll
        for (int a = 0; a < 4; a++)
            #pragma unroll
            for (int s = 0; s < 4; s++)
                acc[a][s] = __builtin_amdgcn_mfma_f32_16x16x32_bf16(af[a], bf[s], acc[a][s], 0, 0, 0);
    }
    // C/D: col = lane&15, row = quad*4 + reg   (guide §3, m89/m91-verified)
    #pragma unroll
    for (int s = 0; s < 4; s++) {
        int col = n_base + s * 16 + l16;
        float bv = bias[col];
        #pragma unroll
        for (int a = 0; a < 4; a++) {
            int row = m_base + a * 16 + quad * 4;
            #pragma unroll
            for (int r = 0; r < 4; r++)
                h[(row + r) * OUT_C + col] = f2bf(acc[a][s][r] + bv);
        }
    }
}

// ---- out[i] = dis[i] * sum_j dis[j] * h[j]; h bf16, channel-chunked (2 x 256ch, 4 MB slice/XCD-L2) ----
__global__ __launch_bounds__(128) void aggregate_k(const int* __restrict__ cnt,
                                                   const uint16_t* __restrict__ nbr,
                                                   const uint32_t* __restrict__ h2,   // h as packed bf16 pairs
                                                   float* __restrict__ out) {
    const int i = blockIdx.x;
    const int half = blockIdx.y;          // channel half: 0 -> [0,256), 1 -> [256,512)
    int m = cnt[i]; if (m > MAX_DEG) m = MAX_DEG;

    __shared__ uint16_t jl[MAX_DEG];
    __shared__ float    dl[MAX_DEG];
    for (int t = threadIdx.x; t < m; t += 128) {
        uint16_t j = nbr[i * MAX_DEG + t];
        jl[t] = j;
        dl[t] = rsqrtf((float)cnt[j]);
    }
    __syncthreads();

    const uint32_t* hp = h2 + half * 128 + threadIdx.x;   // 256 uints per row
    float s0 = 0.f, s1 = 0.f;
    for (int l = 0; l < m; l++) {
        uint32_t u = hp[(int)jl[l] * 256];                 // coalesced 512B per row across block
        float dj = dl[l];
        s0 += dj * __uint_as_float(u << 16);               // channel c (even)
        s1 += dj * __uint_as_float(u & 0xFFFF0000u);       // channel c+1
    }
    float di = rsqrtf((float)m);
    int c = half * 256 + threadIdx.x * 2;
    float2 o = {di * s0, di * s1};
    *(float2*)(out + i * OUT_C + c) = o;
}

extern "C" void kernel_launch(void* const* d_in, const int* in_sizes, int n_in,
                              void* d_out, int out_size, void* d_ws, size_t ws_size,
                              hipStream_t stream) {
    const float* x  = (const float*)d_in[0];
    const int*   ei = (const int*)  d_in[1];
    const float* W  = (const float*)d_in[2];
    const float* b  = (const float*)d_in[3];
    float* out = (float*)d_out;
    char* ws = (char*)d_ws;

    // ws layout (bytes)
    const size_t BITMAP_OFF = 0;                       // 8 MB
    const size_t CNT_OFF    = 8388608;                 // 32 KB
    const size_t NBR_OFF    = CNT_OFF + 32768;         // 8 MB  (u16 * 8192 * 512)
    const size_t XB_OFF     = NBR_OFF + 8388608;       // 8 MB
    const size_t WB_OFF     = XB_OFF + 8388608;        // 512 KB
    const size_t H_OFF      = WB_OFF + 524288;         // 8 MB (bf16)
    uint32_t* bitmap = (uint32_t*)(ws + BITMAP_OFF);
    int*      cnt    = (int*)     (ws + CNT_OFF);
    uint16_t* nbr    = (uint16_t*)(ws + NBR_OFF);
    uint16_t* xb     = (uint16_t*)(ws + XB_OFF);
    uint16_t* wb     = (uint16_t*)(ws + WB_OFF);
    uint16_t* h      = (uint16_t*)(ws + H_OFF);

    hipMemsetAsync(bitmap, 0, 8388608, stream);
    hipMemsetAsync(cnt, 0, 32768, stream);

    f32_to_bf16_k<<<(N_NODES * IN_C / 4 + 255) / 256, 256, 0, stream>>>(x, xb, N_NODES * IN_C);
    f32_to_bf16_k<<<(OUT_C * IN_C / 4 + 255) / 256, 256, 0, stream>>>(W, wb, OUT_C * IN_C);

    build_graph_k<<<(N_EDGES + N_NODES + 255) / 256, 256, 0, stream>>>(ei, bitmap, cnt, nbr);

    gemm_hb_k<<<dim3(OUT_C / 64, N_NODES / 256), 256, 0, stream>>>(xb, wb, b, h);

    aggregate_k<<<dim3(N_NODES, 2), 128, 0, stream>>>(cnt, nbr, (const uint32_t*)h, out);
}